// Round 1
// 164.567 us; speedup vs baseline: 1.0110x; 1.0110x over previous
//
#include <hip/hip_runtime.h>
#include <math.h>

#define IMG_W 3840
#define IMG_H 2160
#define OUTW  60        // output columns per wave strip (64 lanes - 4 halo)
#define R     20        // output rows per strip (2160 = 108 * 20, exact)
#define GROWS (R + 4)   // 24 gray rows per strip
#define MROWS (R + 2)   // 22 mag rows per strip

// idx -> dx [1,1,0,-1,-1,-1,0,1], dy [0,1,1,1,0,-1,-1,-1], packed as (d+1) 2-bit fields
#define DXPACK 0x901A
#define DYPACK 0x1A9

// Sector boundary slopes in the module's scaled-degree space (RAD2DEG = 180/3.14159)
#define T1_SLOPE 0.41421317376456f
#define T2_SLOPE 2.41420676743300f
#define SECT_EPS 3.0e-5f

__device__ __noinline__ int slow_sector(float sx, float sy) {
#pragma clang fp contract(off)
    const float RADF = (float)(180.0 / 3.14159);
    float t = atan2f(sy, sx);
    float wv = ((t * RADF) + 180.0f) / 45.0f;   // exact f32 chain as reference
    float ori = rintf(wv);                      // round-half-even == np.round
    float fr = fabsf(wv - ori);
    if (fr > 0.4995f) {
        // near a rounding tie: redo atan2 in double -> correctly-rounded f32
        double td = atan2((double)sy, (double)sx);
        float t2 = (float)td;
        wv = ((t2 * RADF) + 180.0f) / 45.0f;
        ori = rintf(wv);
    }
    return ((int)ori) & 7;
}

__global__ __launch_bounds__(256, 4) void canny_like_kernel(const float* __restrict__ img,
                                                            float* __restrict__ out) {
#pragma clang fp contract(off)
    // per-wave 4-row circular mag buffer: 4 KB/block (was 22.5 KB), no barriers anywhere
    __shared__ float lds_m[4][4][64];

    const int lane = threadIdx.x;                // 0..63
    const int w    = threadIdx.y;                // wave id in block, 0..3
    const int X0   = (blockIdx.x * 4 + w) * OUTW;
    const int Y0   = blockIdx.y * R;
    const int x    = X0 - 2 + lane;              // gray column owned by this lane
    const bool xok    = (unsigned)x < (unsigned)IMG_W;
    const int  xc     = min(max(x, 0), IMG_W - 1);       // clamped (safe addr, value masked)
    const bool xmok   = (lane >= 1) && (lane <= 62) && xok;   // mag-valid lanes
    const bool xoutok = (lane >= 2) && (lane <= 61);          // output lanes

    const float* im1 = img + (size_t)IMG_W * IMG_H;
    const float* im2 = img + 2 * (size_t)IMG_W * IMG_H;

    // ---- Phase 1: branch-free clamped loads; all 24 gray rows -> registers ----
    // No wave-uniform branch around the loads: the 72 global_load_dword are
    // straight-line and independent -> compiler can batch them (deep MLP).
    float g[GROWS];
#pragma unroll
    for (int k = 0; k < GROWS; ++k) {
        const int  y   = Y0 - 2 + k;
        const bool yok = (unsigned)y < (unsigned)IMG_H;
        const int  yc  = min(max(y, 0), IMG_H - 1);
        const int  o   = yc * IMG_W + xc;
        float c0 = img[o], c1 = im1[o], c2 = im2[o];
        float t = ((c0 + c1) + c2) / 3.0f;       // left-assoc, true div (match ref)
        g[k] = (xok && yok) ? t : 0.0f;
    }

    float* const B = &lds_m[w][0][0];            // wave-private 256-float window

    // rolling shuffled-neighbor window (indices compile-time after full unroll)
    float gl[3], gr[3];
    gl[0] = __shfl_up(g[0], 1);  gr[0] = __shfl_down(g[0], 1);
    gl[1] = __shfl_up(g[1], 1);  gr[1] = __shfl_down(g[1], 1);

    float mc_p  = 0.0f;                          // mag of pending NMS row (lag 1)
    int   off_p = 0;                             // its flat NMS offset (lag 1)

#pragma unroll
    for (int m = 0; m < MROWS; ++m) {
        // mag row m = image row Y0-1+m, from gray rows m, m+1, m+2
        const int i0 = m % 3, i1 = (m + 1) % 3, i2 = (m + 2) % 3;
        gl[i2] = __shfl_up(g[m + 2], 1);
        gr[i2] = __shfl_down(g[m + 2], 1);

        float a00 = gl[i0], a01 = g[m],     a02 = gr[i0];
        float a10 = gl[i1],                 a12 = gr[i1];
        float a20 = gl[i2], a21 = g[m + 2], a22 = gr[i2];
        float sx = a00;                          // exact R4 tap order
        sx = sx - a02;
        sx = sx + 2.0f * a10;
        sx = sx - 2.0f * a12;
        sx = sx + a20;
        sx = sx - a22;
        float sy = a00;
        sy = sy + 2.0f * a01;
        sy = sy + a02;
        sy = sy - a20;
        sy = sy - 2.0f * a21;
        sy = sy - a22;
        float magv = sqrtf(sx * sx + sy * sy);

        // sector -> (dx,dy); eps band falls back to exact atan2 path (rare)
        float ax = fabsf(sx), ay = fabsf(sy);
        float d1 = fmaf(-T1_SLOPE, ax, ay);
        float d2 = fmaf(-T2_SLOPE, ax, ay);
        float sA = ax + ay;
        int dxo, dyo;
        if (__builtin_expect(fabsf(d1) < SECT_EPS * sA || fabsf(d2) < SECT_EPS * sA, 0)) {
            int idx = slow_sector(sx, sy);
            dxo = ((DXPACK >> (2 * idx)) & 3) - 1;
            dyo = ((DYPACK >> (2 * idx)) & 3) - 1;
        } else {
            dxo = (d2 > 0.0f) ? 0 : ((sx > 0.0f) ? -1 : 1);
            dyo = (d1 < 0.0f) ? 0 : ((sy > 0.0f) ? -1 : 1);
        }
        // grad_mag exists only on the HxW grid (dir-conv zero-pads it)
        const bool vok = xmok && ((unsigned)(Y0 - 1 + m) < (unsigned)IMG_H);
        float mag  = vok ? magv : 0.0f;
        int   offv = vok ? (dyo * 64 + dxo) : 0;

        B[(m & 3) * 64 + lane] = mag;            // ds_write into circular slot m&3

        // ---- NMS for row n = m-1 (mag rows m-2..m written; same-wave DS ops
        //      are in-order on CDNA -> no barrier needed). Circular wrap via &255:
        //      (slot*64 + dy*64 + lane + dx) & 255 == ((row+dy)&3)*64 + (lane+dx)
        //      whenever 0 <= lane+dx <= 63 (true for all lanes whose result is used).
        if (m >= 2) {
            const int rp  = ((m - 1) & 3) * 64;  // compile-time constant
            const int ipp = (rp + lane + off_p) & 255;
            const int ipn = (rp + lane - off_p) & 255;
            float mp = B[ipp];                   // mag at (x+dx, n+dy)
            float mn = B[ipn];                   // opposite neighbor (idx+4)
            float res = (fminf(mc_p - mp, mc_p - mn) > 0.0f && mc_p >= 0.2f) ? 1.0f : 0.0f;
            if (xoutok)
                out[(size_t)(Y0 + m - 2) * IMG_W + x] = res;
        }
        mc_p  = mag;
        off_p = offv;
    }
}

extern "C" void kernel_launch(void* const* d_in, const int* in_sizes, int n_in,
                              void* d_out, int out_size, void* d_ws, size_t ws_size,
                              hipStream_t stream) {
    const float* img = (const float*)d_in[0];
    float* out = (float*)d_out;
    // 64 x-strips (60 cols each, 64*60 = 3840 exact) x 108 y-strips (20 rows, exact)
    dim3 grid(64 / 4, IMG_H / R);                // (16, 108) = 1728 blocks, 4 waves each
    dim3 block(64, 4);
    canny_like_kernel<<<grid, block, 0, stream>>>(img, out);
}